// Round 1
// baseline (6893.014 us; speedup 1.0000x reference)
//
#include <hip/hip_runtime.h>
#include <math.h>

#define BATCH 8
#define CIN 512
#define COUT 256
#define HH 64
#define WW 64
#define WDIM 512

// ---------------------------------------------------------------------------
// Kernel 1: s[b,ci] = sum_d style[b,d] * mod_weight[ci,d] * (1/sqrt(512)) + mod_bias[ci]
// one wave per (b, ci)
// ---------------------------------------------------------------------------
__global__ __launch_bounds__(64)
void style_mod_kernel(const float* __restrict__ style,
                      const float* __restrict__ mod_weight,
                      const float* __restrict__ mod_bias,
                      float* __restrict__ s) {
    int idx = blockIdx.x;              // b*CIN + ci
    int b = idx / CIN, ci = idx % CIN;
    int lane = threadIdx.x;
    const float* mw = mod_weight + (size_t)ci * WDIM;
    const float* st = style + (size_t)b * WDIM;
    float acc = 0.f;
    for (int d = lane; d < WDIM; d += 64)
        acc += mw[d] * st[d];
    for (int off = 32; off > 0; off >>= 1)
        acc += __shfl_down(acc, off);
    if (lane == 0) {
        const float mod_scale = 0.04419417382415922f;   // 1/sqrt(512)
        s[idx] = acc * mod_scale + mod_bias[ci];
    }
}

// ---------------------------------------------------------------------------
// Kernel 2: demod[b,co] = rsqrt( sum_{ci,k} (scale*weight[co,ci,k]*s[b,ci])^2 + 1e-8 )
// one 256-thread block per (b, co)
// ---------------------------------------------------------------------------
__global__ __launch_bounds__(256)
void demod_kernel(const float* __restrict__ weight,
                  const float* __restrict__ s,
                  float* __restrict__ demod) {
    int b = blockIdx.x / COUT, co = blockIdx.x % COUT;
    int t = threadIdx.x;
    const float scale = 0.014731391274719739f;          // 1/sqrt(512*9)
    const float* wco = weight + (size_t)co * CIN * 9;
    const float* sb = s + (size_t)b * CIN;
    float acc = 0.f;
    for (int i = t; i < CIN * 9; i += 256) {
        int ci = i / 9;
        float v = scale * wco[i] * sb[ci];
        acc += v * v;
    }
    __shared__ float red[256];
    red[t] = acc;
    __syncthreads();
    if (t < 128) red[t] += red[t + 128];
    __syncthreads();
    if (t < 64) {
        float v = red[t] + red[t + 64];
        for (int off = 32; off > 0; off >>= 1)
            v += __shfl_down(v, off);
        if (t == 0) demod[blockIdx.x] = rsqrtf(v + 1e-8f);
    }
}

// ---------------------------------------------------------------------------
// Kernel 3: fused conv_transpose2d(stride=2) + 4x4 blur.
//
// Parity decomposition: out1[2Y+dy, 2X+dx] ("quad" at coarse (Y,X)):
//   v00 = i11*w[0,0] + i10*w[0,2] + i01*w[2,0] + i00*w[2,2]
//   v01 = i11*w[0,1] + i01*w[2,1]
//   v10 = i11*w[1,0] + i10*w[1,2]
//   v11 = i11*w[1,1]
// where i00..i11 = in[Y-1..Y, X-1..X] (zero-padded) and w is the UNFLIPPED
// modulated weight (flip + correlation == convolution).
// Blur is separable: [0.25, 0.75, 0.75, 0.25] per axis, offsets -1..+2.
//
// Block: 256 threads, handles (b, 4 consecutive co, 16x16 coarse tile).
// Quads needed for the 32x32 fine output tile + blur halo: coarse
// [Y0-1, Y0+16] x [X0-1, X0+16] = 18x18 = 324 positions -> thread t owns
// positions t and t+256 (t<68). Input patch needed: 19x19.
// ---------------------------------------------------------------------------
__global__ __launch_bounds__(256)
void fused_upconv_blur_kernel(const float* __restrict__ input,
                              const float* __restrict__ weight,
                              const float* __restrict__ s,
                              const float* __restrict__ demod,
                              float* __restrict__ out) {
    const int t = threadIdx.x;
    const int tY = blockIdx.x >> 2, tX = blockIdx.x & 3;
    const int cob = blockIdx.y * 4;
    const int b = blockIdx.z;
    const int Y0 = tY * 16, X0 = tX * 16;

    __shared__ __attribute__((aligned(16))) float patch[19][20];
    __shared__ __attribute__((aligned(16))) float wsm[4][12];
    __shared__ __attribute__((aligned(16))) float out1[36][37];
    __shared__ __attribute__((aligned(16))) float tmpb[35][33];

    const float scale = 0.014731391274719739f;          // 1/sqrt(512*9)
    float dm[4];
#pragma unroll
    for (int c = 0; c < 4; ++c)
        dm[c] = demod[b * COUT + cob + c] * scale;

    float a0[4][4], a1[4][4];
#pragma unroll
    for (int c = 0; c < 4; ++c)
#pragma unroll
        for (int q = 0; q < 4; ++q) { a0[c][q] = 0.f; a1[c][q] = 0.f; }

    const int p0 = t, p1 = t + 256;
    const int qY0 = p0 / 18, qX0 = p0 % 18;
    const int qY1s = p1 / 18, qX1 = p1 % 18;
    const bool act1 = (p1 < 324);
    const int qY1 = act1 ? qY1s : 0;   // keep in-bounds; reads guarded anyway

    const float* inb = input + (size_t)b * CIN * HH * WW;
    const float* sb = s + (size_t)b * CIN;

    for (int ci = 0; ci < CIN; ++ci) {
        // ---- stage 19x19 input patch (zero-padded) ----
        const float* inc = inb + (size_t)ci * (HH * WW);
        for (int idx = t; idx < 361; idx += 256) {
            int r = idx / 19, c = idx - r * 19;
            int gr = Y0 - 2 + r, gc = X0 - 2 + c;
            float v = 0.f;
            if ((unsigned)gr < 64u && (unsigned)gc < 64u)
                v = inc[gr * 64 + gc];
            patch[r][c] = v;
        }
        // ---- stage 4x9 modulated weights ----
        if (t < 36) {
            int c = t / 9, k = t - c * 9;
            float sv = sb[ci];
            wsm[c][k] = weight[((size_t)(cob + c) * CIN + ci) * 9 + k] * sv * dm[c];
        }
        __syncthreads();

        const float i00a = patch[qY0][qX0],     i01a = patch[qY0][qX0 + 1];
        const float i10a = patch[qY0 + 1][qX0], i11a = patch[qY0 + 1][qX0 + 1];
        float i00b = 0.f, i01b = 0.f, i10b = 0.f, i11b = 0.f;
        if (act1) {
            i00b = patch[qY1][qX1];     i01b = patch[qY1][qX1 + 1];
            i10b = patch[qY1 + 1][qX1]; i11b = patch[qY1 + 1][qX1 + 1];
        }
#pragma unroll
        for (int c = 0; c < 4; ++c) {
            const float4 wA = *(const float4*)&wsm[c][0];   // w00 w01 w02 w10
            const float4 wB = *(const float4*)&wsm[c][4];   // w11 w12 w20 w21
            const float w8v = wsm[c][8];                    // w22
            a0[c][0] += i11a * wA.x + i10a * wA.z + i01a * wB.z + i00a * w8v;
            a0[c][1] += i11a * wA.y + i01a * wB.w;
            a0[c][2] += i11a * wA.w + i10a * wB.y;
            a0[c][3] += i11a * wB.x;
            if (act1) {
                a1[c][0] += i11b * wA.x + i10b * wA.z + i01b * wB.z + i00b * w8v;
                a1[c][1] += i11b * wA.y + i01b * wB.w;
                a1[c][2] += i11b * wA.w + i10b * wB.y;
                a1[c][3] += i11b * wB.x;
            }
        }
        __syncthreads();
    }

    // ---- epilogue: per co, dump quads to LDS, separable blur, store ----
    const size_t out_base = ((size_t)b * COUT + cob) * 128 * 128;
    for (int c = 0; c < 4; ++c) {
        __syncthreads();
        out1[2 * qY0][2 * qX0]         = a0[c][0];
        out1[2 * qY0][2 * qX0 + 1]     = a0[c][1];
        out1[2 * qY0 + 1][2 * qX0]     = a0[c][2];
        out1[2 * qY0 + 1][2 * qX0 + 1] = a0[c][3];
        if (act1) {
            out1[2 * qY1][2 * qX1]         = a1[c][0];
            out1[2 * qY1][2 * qX1 + 1]     = a1[c][1];
            out1[2 * qY1 + 1][2 * qX1]     = a1[c][2];
            out1[2 * qY1 + 1][2 * qX1 + 1] = a1[c][3];
        }
        __syncthreads();
        // horizontal blur: rows r=0..34 (fine y0-1..y0+33), cols x=0..31
        for (int idx = t; idx < 35 * 32; idx += 256) {
            int r = idx >> 5, x = idx & 31;
            tmpb[r][x] = 0.25f * (out1[r + 1][x + 1] + out1[r + 1][x + 4])
                       + 0.75f * (out1[r + 1][x + 2] + out1[r + 1][x + 3]);
        }
        __syncthreads();
        // vertical blur + store
        float* outc = out + out_base + (size_t)c * 128 * 128;
        for (int idx = t; idx < 1024; idx += 256) {
            int oy = idx >> 5, x = idx & 31;
            float v = 0.25f * (tmpb[oy][x] + tmpb[oy + 3][x])
                    + 0.75f * (tmpb[oy + 1][x] + tmpb[oy + 2][x]);
            outc[(size_t)(2 * Y0 + oy) * 128 + (2 * X0 + x)] = v;
        }
    }
}

// ---------------------------------------------------------------------------
extern "C" void kernel_launch(void* const* d_in, const int* in_sizes, int n_in,
                              void* d_out, int out_size, void* d_ws, size_t ws_size,
                              hipStream_t stream) {
    const float* input      = (const float*)d_in[0];
    const float* style      = (const float*)d_in[1];
    const float* weight     = (const float*)d_in[2];
    const float* mod_weight = (const float*)d_in[3];
    const float* mod_bias   = (const float*)d_in[4];
    float* out = (float*)d_out;

    float* s_buf  = (float*)d_ws;            // BATCH*CIN = 4096 floats
    float* dm_buf = s_buf + BATCH * CIN;     // BATCH*COUT = 2048 floats

    style_mod_kernel<<<BATCH * CIN, 64, 0, stream>>>(style, mod_weight, mod_bias, s_buf);
    demod_kernel<<<BATCH * COUT, 256, 0, stream>>>(weight, s_buf, dm_buf);
    fused_upconv_blur_kernel<<<dim3(16, COUT / 4, BATCH), 256, 0, stream>>>(
        input, weight, s_buf, dm_buf, out);
}

// Round 2
// 544.262 us; speedup vs baseline: 12.6649x; 12.6649x over previous
//
#include <hip/hip_runtime.h>
#include <math.h>

#define BATCH 8
#define CIN 512
#define COUT 256
#define HH 64
#define WW 64
#define WDIM 512

typedef __attribute__((ext_vector_type(8))) short bf16x8;
typedef __attribute__((ext_vector_type(16))) float f32x16;
typedef __attribute__((ext_vector_type(2))) float f32x2;
typedef __attribute__((ext_vector_type(4))) float f32x4;

__device__ __forceinline__ unsigned short f2bf(float f) {
    union { float f; unsigned u; } v; v.f = f;
    unsigned r = v.u + 0x7FFFu + ((v.u >> 16) & 1u);
    return (unsigned short)(r >> 16);
}

// ---------------------------------------------------------------------------
// Kernel 1: s[b,ci] = style @ (mod_weight/sqrt(512)).T + mod_bias
// ---------------------------------------------------------------------------
__global__ __launch_bounds__(64)
void style_mod_kernel(const float* __restrict__ style,
                      const float* __restrict__ mod_weight,
                      const float* __restrict__ mod_bias,
                      float* __restrict__ s) {
    int idx = blockIdx.x;
    int b = idx / CIN, ci = idx % CIN;
    int lane = threadIdx.x;
    const float* mw = mod_weight + (size_t)ci * WDIM;
    const float* st = style + (size_t)b * WDIM;
    float acc = 0.f;
    for (int d = lane; d < WDIM; d += 64) acc += mw[d] * st[d];
    for (int off = 32; off > 0; off >>= 1) acc += __shfl_down(acc, off);
    if (lane == 0) s[idx] = acc * 0.04419417382415922f + mod_bias[ci];
}

// ---------------------------------------------------------------------------
// Kernel 2: demod[b,co] = rsqrt(sum((scale*w*s)^2)+1e-8)
// ---------------------------------------------------------------------------
__global__ __launch_bounds__(256)
void demod_kernel(const float* __restrict__ weight,
                  const float* __restrict__ s,
                  float* __restrict__ demod) {
    int b = blockIdx.x / COUT, co = blockIdx.x % COUT;
    int t = threadIdx.x;
    const float scale = 0.014731391274719739f;
    const float* wco = weight + (size_t)co * CIN * 9;
    const float* sb = s + (size_t)b * CIN;
    float acc = 0.f;
    for (int i = t; i < CIN * 9; i += 256) {
        int ci = i / 9;
        float v = scale * wco[i] * sb[ci];
        acc += v * v;
    }
    __shared__ float red[256];
    red[t] = acc;
    __syncthreads();
    if (t < 128) red[t] += red[t + 128];
    __syncthreads();
    if (t < 64) {
        float v = red[t] + red[t + 64];
        for (int off = 32; off > 0; off >>= 1) v += __shfl_down(v, off);
        if (t == 0) demod[blockIdx.x] = rsqrtf(v + 1e-8f);
    }
}

// ---------------------------------------------------------------------------
// Kernel 3: transpose input [b][ci][y][x] fp32 -> in_t [b][y][x][ci] bf16
// block per (b,y). LDS tile with XOR-swizzled 8-elem chunks for bank spread.
// ---------------------------------------------------------------------------
__global__ __launch_bounds__(256)
void transpose_kernel(const float* __restrict__ in, unsigned short* __restrict__ in_t) {
    int b = blockIdx.x >> 6, y = blockIdx.x & 63;
    __shared__ unsigned short tile[64 * 512];
    int t = threadIdx.x;
    int x = t & 63, cw = t >> 6;
    const float* src = in + (((size_t)b * CIN) * 64 + y) * 64;
    for (int it = 0; it < 128; ++it) {
        int ci = it * 4 + cw;
        float v = src[(size_t)ci * 4096 + x];
        tile[x * 512 + ((((ci >> 3) ^ (x & 7)) << 3) | (ci & 7))] = f2bf(v);
    }
    __syncthreads();
    int wv = t >> 6, lane = t & 63;
    unsigned short* dst = in_t + (((size_t)b * 64 + y) * 64) * 512;
    for (int it = 0; it < 16; ++it) {
        int xx = it * 4 + wv;
        uint4 v = *(const uint4*)&tile[xx * 512 + ((lane ^ (xx & 7)) << 3)];
        *(uint4*)(dst + (size_t)xx * 512 + lane * 8) = v;
    }
}

// ---------------------------------------------------------------------------
// Kernel 4: fold blur into modulated weights.
// W4g[b][pp=py*2+px][tap=dy*3+dx][co][ci] bf16, tap offsets dy,dx in -1..1.
// out[2Y+py,2X+px] = sum_ci sum_tap W4 * in[ci, Y+dy, X+dx]  (zero-padded)
// ---------------------------------------------------------------------------
__global__ __launch_bounds__(256)
void fold_kernel(const float* __restrict__ weight,
                 const float* __restrict__ s,
                 const float* __restrict__ dm,
                 unsigned short* __restrict__ W4g) {
    int idx = blockIdx.x * 256 + threadIdx.x;        // b*co*ci = 1048576
    int b = idx >> 17;
    int rem = idx & 131071;
    int co = rem >> 9, ci = rem & 511;
    float m = 0.014731391274719739f * s[b * CIN + ci] * dm[b * COUT + co];
    const float* wp = weight + ((size_t)co * CIN + ci) * 9;
    float wm[3][3];
#pragma unroll
    for (int k = 0; k < 9; ++k) wm[k / 3][k % 3] = wp[k] * m;
    // T[p][d'][wi]: blur folded per-dim transfer (d' = -1..1 -> 0..2)
    const float T[2][3][3] = {
        {{0.f, .25f, .75f}, {.75f, .75f, .25f}, {.25f, 0.f, 0.f}},
        {{0.f, 0.f, .25f}, {.25f, .75f, .75f}, {.75f, .25f, 0.f}}};
#pragma unroll
    for (int py = 0; py < 2; ++py)
#pragma unroll
        for (int px = 0; px < 2; ++px)
#pragma unroll
            for (int dy = 0; dy < 3; ++dy)
#pragma unroll
                for (int dx = 0; dx < 3; ++dx) {
                    float acc = 0.f;
#pragma unroll
                    for (int ky = 0; ky < 3; ++ky)
#pragma unroll
                        for (int kx = 0; kx < 3; ++kx)
                            acc += T[py][dy][ky] * T[px][dx][kx] * wm[ky][kx];
                    size_t off = ((((size_t)(b * 4 + py * 2 + px) * 9 + dy * 3 + dx) * COUT + co) * CIN) + ci;
                    W4g[off] = f2bf(acc);
                }
}

// ---------------------------------------------------------------------------
// Kernel 5: MFMA conv. Block = (b, py, co64-block, 4 rows x 64 cols), both px.
// 32x32x16 bf16 MFMA, D[m=X pos][n=co]. ci chunked by 16.
// LDS: in_s cells [(r*2+h)*66+cl]*16B, w_s [(tp*2+h)*64+co]*16B  (h = k-half)
// A layout: m=lane&31, k=(lane>>5)*8+j ; B: n=lane&31, k=(lane>>5)*8+j
// C/D:  col=lane&31, row=(reg&3)+8*(reg>>2)+4*(lane>>5)
// ---------------------------------------------------------------------------
#define LDS_IN 0
#define LDS_W 12672
#define LDS_TOTAL 49536

__global__ __launch_bounds__(256, 2)
void conv_kernel(const unsigned short* __restrict__ in_t,
                 const unsigned short* __restrict__ W4g,
                 float* __restrict__ out) {
    __shared__ char lds[LDS_TOTAL];
    int L = blockIdx.x;
    // XCD swizzle: 16 row-siblings of a (b,py,cb) group spaced 8 apart
    int g = ((L >> 7) << 3) | (L & 7);
    int sb = (L >> 3) & 15;
    int b = g >> 3, r = g & 7;
    int py = r >> 2, cb = r & 3;
    int Y0 = sb * 4;
    int t = threadIdx.x, w = t >> 6, lane = t & 63;
    int l31 = lane & 31, hf = lane >> 5;

    const unsigned short* inb = in_t + (size_t)b * 64 * 64 * 512;
    const unsigned short* wb = W4g + ((size_t)(b * 4 + py * 2)) * 9 * COUT * CIN;

    f32x16 acc[2][2][2];
#pragma unroll
    for (int px = 0; px < 2; ++px)
#pragma unroll
        for (int mt = 0; mt < 2; ++mt)
#pragma unroll
            for (int nt = 0; nt < 2; ++nt) acc[px][mt][nt] = (f32x16)0.f;

    for (int c = 0; c < 32; ++c) {
        int ci0 = c << 4;
        __syncthreads();
        // ---- stage input: 396 cells x 2 halves of 16B ----
#pragma unroll
        for (int k = 0; k < 4; ++k) {
            int task = t + (k << 8);
            if (task < 792) {
                int cell = task >> 1, h = task & 1;
                int rr = cell / 66, cl = cell - rr * 66;
                int y = Y0 - 1 + rr, x = cl - 1;
                uint4 v = make_uint4(0u, 0u, 0u, 0u);
                if ((unsigned)y < 64u && (unsigned)x < 64u)
                    v = *(const uint4*)(inb + ((size_t)(y * 64 + x) * 512 + ci0 + h * 8));
                *(uint4*)(lds + LDS_IN + (((rr * 2 + h) * 66 + cl) << 4)) = v;
            }
        }
        // ---- stage weights: 18 (px,tap) x 64 co x 2 halves ----
#pragma unroll
        for (int k = 0; k < 9; ++k) {
            int idx = t + (k << 8);
            int h = idx & 1, co = (idx >> 1) & 63, tp = idx >> 7;
            uint4 v = *(const uint4*)(wb + (size_t)tp * (COUT * CIN) +
                                      (size_t)(cb * 64 + co) * CIN + ci0 + h * 8);
            *(uint4*)(lds + LDS_W + (((tp * 2 + h) * 64 + co) << 4)) = v;
        }
        __syncthreads();
        // ---- compute: 9 taps x 2 px x 4 MFMA ----
#pragma unroll
        for (int tap = 0; tap < 9; ++tap) {
            int dy = tap / 3 - 1, dx = tap % 3 - 1;
            int rbase = ((w + 1 + dy) * 2 + hf) * 66;
            bf16x8 a0 = *(const bf16x8*)(lds + LDS_IN + ((rbase + 1 + l31 + dx) << 4));
            bf16x8 a1 = *(const bf16x8*)(lds + LDS_IN + ((rbase + 33 + l31 + dx) << 4));
#pragma unroll
            for (int px = 0; px < 2; ++px) {
                int tp = px * 9 + tap;
                bf16x8 b0 = *(const bf16x8*)(lds + LDS_W + (((tp * 2 + hf) * 64 + l31) << 4));
                bf16x8 b1 = *(const bf16x8*)(lds + LDS_W + (((tp * 2 + hf) * 64 + 32 + l31) << 4));
                acc[px][0][0] = __builtin_amdgcn_mfma_f32_32x32x16_bf16(a0, b0, acc[px][0][0], 0, 0, 0);
                acc[px][0][1] = __builtin_amdgcn_mfma_f32_32x32x16_bf16(a0, b1, acc[px][0][1], 0, 0, 0);
                acc[px][1][0] = __builtin_amdgcn_mfma_f32_32x32x16_bf16(a1, b0, acc[px][1][0], 0, 0, 0);
                acc[px][1][1] = __builtin_amdgcn_mfma_f32_32x32x16_bf16(a1, b1, acc[px][1][1], 0, 0, 0);
            }
        }
    }
    __syncthreads();
    // ---- epilogue: per-wave LDS transpose to (co, fx), coalesced stores ----
    float* ob = (float*)(lds + w * 9216);   // [64 co][36 floats pitch] (144B)
    int fy = 2 * (Y0 + w) + py;
    float* outb = out + (((size_t)b * COUT + cb * 64) * 128 + fy) * 128;
#pragma unroll
    for (int mt = 0; mt < 2; ++mt)
#pragma unroll
        for (int hh = 0; hh < 2; ++hh) {
            int fx0 = mt * 64 + hh * 32;
#pragma unroll
            for (int nt = 0; nt < 2; ++nt)
#pragma unroll
                for (int j = 0; j < 8; ++j) {
                    int reg = hh * 8 + j;
                    int Xl = (j & 3) + ((j >> 2) << 3) + (hf << 2);
                    int cw = nt * 32 + l31;
                    f32x2 v;
                    v.x = acc[0][mt][nt][reg];
                    v.y = acc[1][mt][nt][reg];
                    *(f32x2*)(ob + cw * 36 + Xl * 2) = v;
                }
            asm volatile("s_waitcnt lgkmcnt(0)" ::: "memory");
#pragma unroll
            for (int rr = 0; rr < 2; ++rr) {
                int co_r = (lane >> 1) + rr * 32;
                const float* srcp = ob + co_r * 36 + (lane & 1) * 16;
                float* dstp = outb + (size_t)co_r * 16384 + fx0 + (lane & 1) * 16;
#pragma unroll
                for (int q = 0; q < 4; ++q)
                    *(f32x4*)(dstp + q * 4) = *(const f32x4*)(srcp + q * 4);
            }
            asm volatile("s_waitcnt lgkmcnt(0)" ::: "memory");
        }
}

// ---------------------------------------------------------------------------
// FALLBACK (round-1 fp32 path) if ws_size too small for the MFMA pipeline
// ---------------------------------------------------------------------------
__global__ __launch_bounds__(256)
void fused_upconv_blur_kernel(const float* __restrict__ input,
                              const float* __restrict__ weight,
                              const float* __restrict__ s,
                              const float* __restrict__ demod,
                              float* __restrict__ out) {
    const int t = threadIdx.x;
    const int tY = blockIdx.x >> 2, tX = blockIdx.x & 3;
    const int cob = blockIdx.y * 4;
    const int b = blockIdx.z;
    const int Y0 = tY * 16, X0 = tX * 16;
    __shared__ __attribute__((aligned(16))) float patch[19][20];
    __shared__ __attribute__((aligned(16))) float wsm[4][12];
    __shared__ __attribute__((aligned(16))) float out1[36][37];
    __shared__ __attribute__((aligned(16))) float tmpb[35][33];
    const float scale = 0.014731391274719739f;
    float dmv[4];
#pragma unroll
    for (int c = 0; c < 4; ++c) dmv[c] = demod[b * COUT + cob + c] * scale;
    float a0[4][4], a1[4][4];
#pragma unroll
    for (int c = 0; c < 4; ++c)
#pragma unroll
        for (int q = 0; q < 4; ++q) { a0[c][q] = 0.f; a1[c][q] = 0.f; }
    const int p0 = t, p1 = t + 256;
    const int qY0 = p0 / 18, qX0 = p0 % 18;
    const int qY1s = p1 / 18, qX1 = p1 % 18;
    const bool act1 = (p1 < 324);
    const int qY1 = act1 ? qY1s : 0;
    const float* inb = input + (size_t)b * CIN * HH * WW;
    const float* sb = s + (size_t)b * CIN;
    for (int ci = 0; ci < CIN; ++ci) {
        const float* inc = inb + (size_t)ci * (HH * WW);
        for (int idx = t; idx < 361; idx += 256) {
            int rr = idx / 19, cc = idx - rr * 19;
            int gr = Y0 - 2 + rr, gc = X0 - 2 + cc;
            float v = 0.f;
            if ((unsigned)gr < 64u && (unsigned)gc < 64u) v = inc[gr * 64 + gc];
            patch[rr][cc] = v;
        }
        if (t < 36) {
            int c = t / 9, k = t - c * 9;
            wsm[c][k] = weight[((size_t)(cob + c) * CIN + ci) * 9 + k] * sb[ci] * dmv[c];
        }
        __syncthreads();
        const float i00a = patch[qY0][qX0], i01a = patch[qY0][qX0 + 1];
        const float i10a = patch[qY0 + 1][qX0], i11a = patch[qY0 + 1][qX0 + 1];
        float i00b = 0.f, i01b = 0.f, i10b = 0.f, i11b = 0.f;
        if (act1) {
            i00b = patch[qY1][qX1]; i01b = patch[qY1][qX1 + 1];
            i10b = patch[qY1 + 1][qX1]; i11b = patch[qY1 + 1][qX1 + 1];
        }
#pragma unroll
        for (int c = 0; c < 4; ++c) {
            const float4 wA = *(const float4*)&wsm[c][0];
            const float4 wB = *(const float4*)&wsm[c][4];
            const float w8v = wsm[c][8];
            a0[c][0] += i11a * wA.x + i10a * wA.z + i01a * wB.z + i00a * w8v;
            a0[c][1] += i11a * wA.y + i01a * wB.w;
            a0[c][2] += i11a * wA.w + i10a * wB.y;
            a0[c][3] += i11a * wB.x;
            if (act1) {
                a1[c][0] += i11b * wA.x + i10b * wA.z + i01b * wB.z + i00b * w8v;
                a1[c][1] += i11b * wA.y + i01b * wB.w;
                a1[c][2] += i11b * wA.w + i10b * wB.y;
                a1[c][3] += i11b * wB.x;
            }
        }
        __syncthreads();
    }
    const size_t out_base = ((size_t)b * COUT + cob) * 128 * 128;
    for (int c = 0; c < 4; ++c) {
        __syncthreads();
        out1[2 * qY0][2 * qX0] = a0[c][0];
        out1[2 * qY0][2 * qX0 + 1] = a0[c][1];
        out1[2 * qY0 + 1][2 * qX0] = a0[c][2];
        out1[2 * qY0 + 1][2 * qX0 + 1] = a0[c][3];
        if (act1) {
            out1[2 * qY1][2 * qX1] = a1[c][0];
            out1[2 * qY1][2 * qX1 + 1] = a1[c][1];
            out1[2 * qY1 + 1][2 * qX1] = a1[c][2];
            out1[2 * qY1 + 1][2 * qX1 + 1] = a1[c][3];
        }
        __syncthreads();
        for (int idx = t; idx < 35 * 32; idx += 256) {
            int rr = idx >> 5, x = idx & 31;
            tmpb[rr][x] = 0.25f * (out1[rr + 1][x + 1] + out1[rr + 1][x + 4])
                        + 0.75f * (out1[rr + 1][x + 2] + out1[rr + 1][x + 3]);
        }
        __syncthreads();
        float* outc = out + out_base + (size_t)c * 128 * 128;
        for (int idx = t; idx < 1024; idx += 256) {
            int oy = idx >> 5, x = idx & 31;
            float v = 0.25f * (tmpb[oy][x] + tmpb[oy + 3][x])
                    + 0.75f * (tmpb[oy + 1][x] + tmpb[oy + 2][x]);
            outc[(size_t)(2 * Y0 + oy) * 128 + (2 * X0 + x)] = v;
        }
    }
}

// ---------------------------------------------------------------------------
extern "C" void kernel_launch(void* const* d_in, const int* in_sizes, int n_in,
                              void* d_out, int out_size, void* d_ws, size_t ws_size,
                              hipStream_t stream) {
    const float* input      = (const float*)d_in[0];
    const float* style      = (const float*)d_in[1];
    const float* weight     = (const float*)d_in[2];
    const float* mod_weight = (const float*)d_in[3];
    const float* mod_bias   = (const float*)d_in[4];
    float* out = (float*)d_out;

    // ws layout: s(16KB) | dm(8KB) | pad | in_t bf16 (33.5MB) | W4g bf16 (75.5MB)
    const size_t OFF_S = 0, OFF_DM = 16384, OFF_INT = 32768;
    const size_t OFF_W4 = OFF_INT + (size_t)BATCH * 64 * 64 * CIN * 2;      // 33587200
    const size_t WS_NEEDED = OFF_W4 + (size_t)BATCH * 4 * 9 * COUT * CIN * 2; // 109084672

    float* s_buf  = (float*)((char*)d_ws + OFF_S);
    float* dm_buf = (float*)((char*)d_ws + OFF_DM);

    style_mod_kernel<<<BATCH * CIN, 64, 0, stream>>>(style, mod_weight, mod_bias, s_buf);
    demod_kernel<<<BATCH * COUT, 256, 0, stream>>>(weight, s_buf, dm_buf);

    if (ws_size >= WS_NEEDED) {
        unsigned short* in_t = (unsigned short*)((char*)d_ws + OFF_INT);
        unsigned short* W4g  = (unsigned short*)((char*)d_ws + OFF_W4);
        transpose_kernel<<<BATCH * 64, 256, 0, stream>>>(input, in_t);
        fold_kernel<<<(BATCH * COUT * CIN) / 256, 256, 0, stream>>>(weight, s_buf, dm_buf, W4g);
        conv_kernel<<<1024, 256, 0, stream>>>(in_t, W4g, out);
    } else {
        fused_upconv_blur_kernel<<<dim3(16, COUT / 4, BATCH), 256, 0, stream>>>(
            input, weight, s_buf, dm_buf, out);
    }
}